// Round 2
// baseline (270.855 us; speedup 1.0000x reference)
//
#include <hip/hip_runtime.h>

// Problem constants (from reference): B=32, CIN=64, COUT=64, H=W=128, 1x1 conv
#define CIN   64
#define COUT  64
#define HW    16384          // 128*128
#define NPIX  (32 * HW)      // B * H * W = 524288

// ---------------------------------------------------------------------------
// Prep kernel: pack weights to int8 dwords + fold requant params.
// wp[o*16 + k] holds (w[o][4k..4k+3] - wzp[o]) as 4 signed bytes.
// params[o] = { scale_o, bias_o/os + ozp, as_float(sum_ci(w'-wzp)), 0 }
// ---------------------------------------------------------------------------
__global__ void prep_kernel(const int* __restrict__ w,
                            const float* __restrict__ wscale,
                            const int* __restrict__ wzp,
                            const float* __restrict__ bias,
                            const float* __restrict__ is_p,
                            const float* __restrict__ os_p,
                            const int* __restrict__ ozp_p,
                            int* __restrict__ wp,
                            float4* __restrict__ params) {
    int o = threadIdx.x;
    if (o >= COUT) return;
    int zp = wzp[o];
    int sum = 0;
    #pragma unroll
    for (int k = 0; k < 16; ++k) {
        int c0 = w[o * CIN + 4 * k + 0] - zp;
        int c1 = w[o * CIN + 4 * k + 1] - zp;
        int c2 = w[o * CIN + 4 * k + 2] - zp;
        int c3 = w[o * CIN + 4 * k + 3] - zp;
        sum += c0 + c1 + c2 + c3;
        wp[o * 16 + k] = (c0 & 0xff) | ((c1 & 0xff) << 8) |
                         ((c2 & 0xff) << 16) | ((c3 & 0xff) << 24);
    }
    float scale = is_p[0] * wscale[o] / os_p[0];
    float bterm = bias[o] / os_p[0] + (float)ozp_p[0];
    float4 pr;
    pr.x = scale;
    pr.y = bterm;
    pr.z = __int_as_float(sum);
    pr.w = 0.0f;
    params[o] = pr;
}

// ---------------------------------------------------------------------------
// Main kernel: 4 pixels / thread. int4 coalesced loads of x (one ci, 4 px),
// pack (x-128) into int8 dwords (XOR 0x80 trick), sdot4 against LDS-staged
// packed weights, requant, int4 store (output dtype is int32 — harness reads
// the uint8-reference output as np.int32).
// ---------------------------------------------------------------------------
__global__ __launch_bounds__(256) void conv_kernel(
    const int* __restrict__ x,
    const int* __restrict__ wp_g,
    const float4* __restrict__ params_g,
    const int* __restrict__ izp_p,
    int* __restrict__ out) {

    __shared__ int4  s_wp[COUT * 4];   // 64 outs x 16 dwords (as 4x int4) = 4 KB
    __shared__ float4 s_par[COUT];     // 1 KB

    int tid = threadIdx.x;
    // stage weights: 256 int4 = 1024 dwords, one per thread
    s_wp[tid] = ((const int4*)wp_g)[tid];
    if (tid < COUT) s_par[tid] = params_g[tid];
    int izp_adj = izp_p[0] - 128;      // 0 for the reference inputs; exact otherwise
    __syncthreads();

    int t  = blockIdx.x * 256 + tid;
    int g4 = t * 4;                    // first of 4 consecutive pixels
    int b  = g4 >> 14;                 // / HW
    int p  = g4 & (HW - 1);

    const int* xb = x + b * (CIN * HW) + p;

    // px[j][cg]: pixel j, channel group cg (4 channels packed as signed bytes)
    int px[4][16];
    #pragma unroll
    for (int cg = 0; cg < 16; ++cg) {
        int4 v0 = *(const int4*)(xb + (4 * cg + 0) * HW);
        int4 v1 = *(const int4*)(xb + (4 * cg + 1) * HW);
        int4 v2 = *(const int4*)(xb + (4 * cg + 2) * HW);
        int4 v3 = *(const int4*)(xb + (4 * cg + 3) * HW);
        // values are 0..255 in low byte; (x-128) as int8 == byte XOR 0x80
        px[0][cg] = (v0.x | (v1.x << 8) | (v2.x << 16) | (v3.x << 24)) ^ 0x80808080;
        px[1][cg] = (v0.y | (v1.y << 8) | (v2.y << 16) | (v3.y << 24)) ^ 0x80808080;
        px[2][cg] = (v0.z | (v1.z << 8) | (v2.z << 16) | (v3.z << 24)) ^ 0x80808080;
        px[3][cg] = (v0.w | (v1.w << 8) | (v2.w << 16) | (v3.w << 24)) ^ 0x80808080;
    }

    int* ob = out + b * (COUT * HW) + p;

    #pragma unroll 2
    for (int o = 0; o < COUT; ++o) {
        int4 w0 = s_wp[o * 4 + 0];
        int4 w1 = s_wp[o * 4 + 1];
        int4 w2 = s_wp[o * 4 + 2];
        int4 w3 = s_wp[o * 4 + 3];
        float4 pr = s_par[o];
        int wsum = __float_as_int(pr.z);
        int base = -izp_adj * wsum;     // izp correction (0 here)

        int4 r;
        #pragma unroll
        for (int j = 0; j < 4; ++j) {
            int acc = base;
            acc = __builtin_amdgcn_sdot4(px[j][0],  w0.x, acc, false);
            acc = __builtin_amdgcn_sdot4(px[j][1],  w0.y, acc, false);
            acc = __builtin_amdgcn_sdot4(px[j][2],  w0.z, acc, false);
            acc = __builtin_amdgcn_sdot4(px[j][3],  w0.w, acc, false);
            acc = __builtin_amdgcn_sdot4(px[j][4],  w1.x, acc, false);
            acc = __builtin_amdgcn_sdot4(px[j][5],  w1.y, acc, false);
            acc = __builtin_amdgcn_sdot4(px[j][6],  w1.z, acc, false);
            acc = __builtin_amdgcn_sdot4(px[j][7],  w1.w, acc, false);
            acc = __builtin_amdgcn_sdot4(px[j][8],  w2.x, acc, false);
            acc = __builtin_amdgcn_sdot4(px[j][9],  w2.y, acc, false);
            acc = __builtin_amdgcn_sdot4(px[j][10], w2.z, acc, false);
            acc = __builtin_amdgcn_sdot4(px[j][11], w2.w, acc, false);
            acc = __builtin_amdgcn_sdot4(px[j][12], w3.x, acc, false);
            acc = __builtin_amdgcn_sdot4(px[j][13], w3.y, acc, false);
            acc = __builtin_amdgcn_sdot4(px[j][14], w3.z, acc, false);
            acc = __builtin_amdgcn_sdot4(px[j][15], w3.w, acc, false);
            float f = fmaf((float)acc, pr.x, pr.y);
            f = rintf(f);                         // v_rndne: round-half-even, matches jnp.round
            f = fminf(fmaxf(f, 0.0f), 255.0f);    // clamp to uint8 range
            (&r.x)[j] = (int)f;                   // output dtype is int32
        }
        *(int4*)(ob + o * HW) = r;
    }
}

extern "C" void kernel_launch(void* const* d_in, const int* in_sizes, int n_in,
                              void* d_out, int out_size, void* d_ws, size_t ws_size,
                              hipStream_t stream) {
    const int*   x      = (const int*)d_in[0];     // [32,64,128,128] int32 (uint8 vals)
    const float* is_p   = (const float*)d_in[1];   // input_scale
    const int*   izp_p  = (const int*)d_in[2];     // input_zero_point
    const int*   w      = (const int*)d_in[3];     // [64,64,1,1] int32
    const float* wscale = (const float*)d_in[4];   // [64]
    const int*   wzp    = (const int*)d_in[5];     // [64]
    const float* bias   = (const float*)d_in[6];   // [64]
    const float* os_p   = (const float*)d_in[7];   // output_scale
    const int*   ozp_p  = (const int*)d_in[8];     // output_zero_point

    int* out = (int*)d_out;

    int*    wp     = (int*)d_ws;                       // 4096 B
    float4* params = (float4*)((char*)d_ws + 4096);    // 1024 B

    prep_kernel<<<1, 64, 0, stream>>>(w, wscale, wzp, bias, is_p, os_p, ozp_p, wp, params);

    // 524288 pixels / 4 per thread / 256 per block = 512 blocks
    conv_kernel<<<512, 256, 0, stream>>>(x, wp, params, izp_p, out);
}

// Round 3
// 253.350 us; speedup vs baseline: 1.0691x; 1.0691x over previous
//
#include <hip/hip_runtime.h>

// Problem constants (from reference): B=32, CIN=64, COUT=64, H=W=128, 1x1 conv
#define CIN   64
#define COUT  64
#define HW    16384          // 128*128
#define NPIX  (32 * HW)      // B * H * W = 524288

// ---------------------------------------------------------------------------
// Prep kernel: pack weights to int8 dwords + fold requant params.
// wp[o*16 + k] holds (w[o][4k..4k+3] - wzp[o]) as 4 signed bytes.
// params[o] = { scale_o, bias_o/os + ozp, as_float(sum_ci(w'-wzp)), 0 }
// ---------------------------------------------------------------------------
__global__ void prep_kernel(const int* __restrict__ w,
                            const float* __restrict__ wscale,
                            const int* __restrict__ wzp,
                            const float* __restrict__ bias,
                            const float* __restrict__ is_p,
                            const float* __restrict__ os_p,
                            const int* __restrict__ ozp_p,
                            int* __restrict__ wp,
                            float4* __restrict__ params) {
    int o = threadIdx.x;
    if (o >= COUT) return;
    int zp = wzp[o];
    int sum = 0;
    #pragma unroll
    for (int k = 0; k < 16; ++k) {
        int c0 = w[o * CIN + 4 * k + 0] - zp;
        int c1 = w[o * CIN + 4 * k + 1] - zp;
        int c2 = w[o * CIN + 4 * k + 2] - zp;
        int c3 = w[o * CIN + 4 * k + 3] - zp;
        sum += c0 + c1 + c2 + c3;
        wp[o * 16 + k] = (c0 & 0xff) | ((c1 & 0xff) << 8) |
                         ((c2 & 0xff) << 16) | ((c3 & 0xff) << 24);
    }
    float scale = is_p[0] * wscale[o] / os_p[0];
    float bterm = bias[o] / os_p[0] + (float)ozp_p[0];
    float4 pr;
    pr.x = scale;
    pr.y = bterm;
    pr.z = __int_as_float(sum);
    pr.w = 0.0f;
    params[o] = pr;
}

// ---------------------------------------------------------------------------
// Main kernel: 1 pixel / thread (2048 blocks -> 32 waves/CU for latency
// hiding). Coalesced dword loads of x (64 lanes x 4B = 256B/instr), pack
// (x-128) into int8 dwords (XOR 0x80 trick), sdot4 against LDS-broadcast
// packed weights, requant, nontemporal dword stores (write-once stream;
// keep x resident in L3).
// ---------------------------------------------------------------------------
__global__ __launch_bounds__(256) void conv_kernel(
    const int* __restrict__ x,
    const int* __restrict__ wp_g,
    const float4* __restrict__ params_g,
    const int* __restrict__ izp_p,
    int* __restrict__ out) {

    __shared__ int4  s_wp[COUT * 4];   // 64 outs x 16 dwords (as 4x int4) = 4 KB
    __shared__ float4 s_par[COUT];     // 1 KB

    int tid = threadIdx.x;
    // stage weights: 256 int4 = 1024 dwords, one per thread
    s_wp[tid] = ((const int4*)wp_g)[tid];
    if (tid < COUT) s_par[tid] = params_g[tid];
    int izp_adj = izp_p[0] - 128;      // 0 for the reference inputs; exact otherwise
    __syncthreads();

    int t = blockIdx.x * 256 + tid;    // pixel index 0..524287
    int b = t >> 14;                   // / HW
    int p = t & (HW - 1);

    const int* xb = x + b * (CIN * HW) + p;

    // px[cg]: channel group cg = 4 channels packed as signed bytes (x-128)
    int px[16];
    #pragma unroll
    for (int cg = 0; cg < 16; ++cg) {
        int v0 = xb[(4 * cg + 0) * HW];
        int v1 = xb[(4 * cg + 1) * HW];
        int v2 = xb[(4 * cg + 2) * HW];
        int v3 = xb[(4 * cg + 3) * HW];
        // values are 0..255 in low byte; (x-128) as int8 == byte XOR 0x80
        px[cg] = (v0 | (v1 << 8) | (v2 << 16) | (v3 << 24)) ^ 0x80808080;
    }

    int* ob = out + b * (COUT * HW) + p;

    #pragma unroll 8
    for (int o = 0; o < COUT; ++o) {
        int4 w0 = s_wp[o * 4 + 0];
        int4 w1 = s_wp[o * 4 + 1];
        int4 w2 = s_wp[o * 4 + 2];
        int4 w3 = s_wp[o * 4 + 3];
        float4 pr = s_par[o];
        int wsum = __float_as_int(pr.z);
        int acc = -izp_adj * wsum;      // izp correction (0 here)

        acc = __builtin_amdgcn_sdot4(px[0],  w0.x, acc, false);
        acc = __builtin_amdgcn_sdot4(px[1],  w0.y, acc, false);
        acc = __builtin_amdgcn_sdot4(px[2],  w0.z, acc, false);
        acc = __builtin_amdgcn_sdot4(px[3],  w0.w, acc, false);
        acc = __builtin_amdgcn_sdot4(px[4],  w1.x, acc, false);
        acc = __builtin_amdgcn_sdot4(px[5],  w1.y, acc, false);
        acc = __builtin_amdgcn_sdot4(px[6],  w1.z, acc, false);
        acc = __builtin_amdgcn_sdot4(px[7],  w1.w, acc, false);
        acc = __builtin_amdgcn_sdot4(px[8],  w2.x, acc, false);
        acc = __builtin_amdgcn_sdot4(px[9],  w2.y, acc, false);
        acc = __builtin_amdgcn_sdot4(px[10], w2.z, acc, false);
        acc = __builtin_amdgcn_sdot4(px[11], w2.w, acc, false);
        acc = __builtin_amdgcn_sdot4(px[12], w3.x, acc, false);
        acc = __builtin_amdgcn_sdot4(px[13], w3.y, acc, false);
        acc = __builtin_amdgcn_sdot4(px[14], w3.z, acc, false);
        acc = __builtin_amdgcn_sdot4(px[15], w3.w, acc, false);

        float f = fmaf((float)acc, pr.x, pr.y);
        f = rintf(f);                         // v_rndne: round-half-even, matches jnp.round
        f = fminf(fmaxf(f, 0.0f), 255.0f);    // clamp to uint8 range
        __builtin_nontemporal_store((int)f, ob + o * HW);
    }
}

extern "C" void kernel_launch(void* const* d_in, const int* in_sizes, int n_in,
                              void* d_out, int out_size, void* d_ws, size_t ws_size,
                              hipStream_t stream) {
    const int*   x      = (const int*)d_in[0];     // [32,64,128,128] int32 (uint8 vals)
    const float* is_p   = (const float*)d_in[1];   // input_scale
    const int*   izp_p  = (const int*)d_in[2];     // input_zero_point
    const int*   w      = (const int*)d_in[3];     // [64,64,1,1] int32
    const float* wscale = (const float*)d_in[4];   // [64]
    const int*   wzp    = (const int*)d_in[5];     // [64]
    const float* bias   = (const float*)d_in[6];   // [64]
    const float* os_p   = (const float*)d_in[7];   // output_scale
    const int*   ozp_p  = (const int*)d_in[8];     // output_zero_point

    int* out = (int*)d_out;

    int*    wp     = (int*)d_ws;                       // 4096 B
    float4* params = (float4*)((char*)d_ws + 4096);    // 1024 B

    prep_kernel<<<1, 64, 0, stream>>>(w, wscale, wzp, bias, is_p, os_p, ozp_p, wp, params);

    // 524288 pixels / 1 per thread / 256 per block = 2048 blocks
    conv_kernel<<<2048, 256, 0, stream>>>(x, wp, params, izp_p, out);
}